// Round 1
// 3837.267 us; speedup vs baseline: 1.9990x; 1.9990x over previous
//
#include <hip/hip_runtime.h>
#include <hip/hip_bf16.h>

typedef __hip_bfloat16 bf16;
typedef __attribute__((ext_vector_type(8))) short s16x8;   // 8 bf16 (MFMA A/B frag)
typedef __attribute__((ext_vector_type(4))) float f32x4;   // MFMA C/D frag
typedef __attribute__((ext_vector_type(4))) int   i32x4;

#define BATCH   64
#define SEQ     256
#define HID     1024
#define GATES   4096
#define NWG     256
#define THREADS 256
#define UNITS   8            // hidden units per WG
#define NCOLS   32           // gate columns per WG (4 gates x 8 units)
#define ROWSTRIDE 2056       // 2048 K + 8 pad elems (LDS bank de-alias)
#define GSTRIDE 33           // gates LDS row stride (+1 pad)
#define BH      (BATCH * HID)

#define H0_SLOTS 4           // layer0 h ring (lets layer0 run ahead)
#define H1_SLOTS 2
#define FLAG_ELEMS ((size_t)6 * BH)            // flags start after h slots (bf16 elems)
#define WS_BYTES  (FLAG_ELEMS * 2 + 34 * 128)  // layout unchanged from prev version

#define OUT_HN  ((size_t)BATCH * SEQ * HID)
#define OUT_CN  (OUT_HN + 2ull * BATCH * HID)

// fp32 -> bf16 bits, round-to-nearest-even
__device__ __forceinline__ short f2bf(float f) {
    unsigned int u = __builtin_bit_cast(unsigned int, f);
    u = (u + 0x7fffu + ((u >> 16) & 1u)) >> 16;
    return (short)u;
}

// coherent 16B load: sc0 sc1 bypasses L1 + per-XCD L2, reads at device coherent
// point (Infinity Cache). Single instruction, vmcnt-only (never flat/lgkmcnt).
__device__ __forceinline__ s16x8 ldg16(const bf16* p) {
    i32x4 r;
    asm volatile("global_load_dwordx4 %0, %1, off sc0 sc1" : "=v"(r) : "v"(p));
    return __builtin_bit_cast(s16x8, r);
}

// Batched coherent GEMM slice: issue ALL 32 fragment loads back-to-back (latency
// paid once, not 32x), one vmcnt(0), sched_barrier (rule #18), then MFMA loop.
// xrow/s0/s1 already include the +kq lane offset.
__device__ __forceinline__ void gemm_bt(const bf16* xrow, const bf16* s0, const bf16* s1,
                                        f32x4& a0, f32x4& a1)
{
    s16x8 ha[32];
#pragma unroll
    for (int kk = 0; kk < 32; ++kk) ha[kk] = ldg16(xrow + kk * 32);
    asm volatile("s_waitcnt vmcnt(0)");
    __builtin_amdgcn_sched_barrier(0);
#pragma unroll
    for (int kk = 0; kk < 32; ++kk) {
        s16x8 b0 = *(const s16x8*)(s0 + kk * 32);
        s16x8 b1 = *(const s16x8*)(s1 + kk * 32);
        a0 = __builtin_amdgcn_mfma_f32_16x16x32_bf16(ha[kk], b0, a0, 0, 0, 0);
        a1 = __builtin_amdgcn_mfma_f32_16x16x32_bf16(ha[kk], b1, a1, 0, 0, 0);
    }
}

// lanes 0..15 poll the 16 group lines of one layer in parallel (flat flag tree:
// no root promotion RMWs on the producer tail). Condition "every group >= tgt"
// == "all 128 WGs of that layer completed the step". Always ends in a barrier.
__device__ __forceinline__ void wait16(unsigned int* base, int tid, int tgt) {
    if (tid < 16 && tgt > 0) {
        unsigned int* p = base + tid * 32;
        while ((int)__hip_atomic_load(p, __ATOMIC_RELAXED, __HIP_MEMORY_SCOPE_AGENT) < tgt)
            __builtin_amdgcn_s_sleep(1);
    }
    __syncthreads();
}

__global__ void ws_init(unsigned int* p, int n) {
    for (int i = blockIdx.x * blockDim.x + threadIdx.x; i < n; i += gridDim.x * blockDim.x)
        p[i] = 0u;
}

__global__ void __launch_bounds__(THREADS, 1)
lstm_enc(const int* __restrict__ src, const float* __restrict__ Wemb,
         const float* __restrict__ Wih, const float* __restrict__ Whh,
         const float* __restrict__ bih, const float* __restrict__ bhh,
         float* __restrict__ out, bf16* __restrict__ hbuf)
{
    __shared__ __align__(16) bf16 slab[NCOLS][ROWSTRIDE];   // 131,584 B (persists)
    __shared__ float gates[BATCH][GSTRIDE];                 // 8,448 B
    __shared__ float bias[NCOLS];

    const int wg    = blockIdx.x;
    const int layer = wg >> 7;                 // 0-127: layer0, 128-255: layer1
    const int wgl   = wg & 127;
    const int j0    = wgl * UNITS;
    const int tid   = threadIdx.x;
    const int lane  = tid & 63;
    const int wave  = tid >> 6;
    const int m     = lane & 15;
    const int kq    = (lane >> 4) * 8;
    const int b_a   = wave * 16 + m;           // batch row this lane loads for A

    // ---- weight slab: rows = [i8|f8|g8|o8], K = [W_ih row | W_hh row], fp32->bf16 ----
    for (int r = 0; r < NCOLS; ++r) {
        int g = r >> 3, u = r & 7;
        size_t grow = (size_t)layer * GATES * HID + (size_t)(g * HID + j0 + u) * HID;
        int k = tid * 8;                       // 256 threads x 8 = 2048 exact
        const float* s = (k < HID) ? (Wih + grow + k) : (Whh + grow + (k - HID));
        s16x8 v;
#pragma unroll
        for (int j = 0; j < 8; ++j) v[j] = f2bf(s[j]);
        *(s16x8*)&slab[r][k] = v;
    }
    if (tid < NCOLS) {
        int g = tid >> 3, u = tid & 7;
        int off = layer * GATES + g * HID + j0 + u;
        bias[tid] = bih[off] + bhh[off];
    }
    __syncthreads();

    bf16* h0 = hbuf;                           // [4][B][H] ring
    bf16* h1 = hbuf + H0_SLOTS * BH;           // [2][B][H] ring
    unsigned int* flags = (unsigned int*)(hbuf + FLAG_ELEMS);
    // line i = flags + i*32 (128 B apart). 0-15: L0 groups, 16-31: L1 groups
    unsigned int* grp = flags + (16 * layer + (wgl >> 3)) * 32;
    unsigned int* g0  = flags;                 // layer0 group lines
    unsigned int* g1  = flags + 16 * 32;       // layer1 group lines

    // epilogue mapping: thread -> (bb = tid>>2, u0 = 2*(tid&3)); c-state in registers
    const int bb = tid >> 2;
    const int u0 = (tid & 3) * 2;
    float c_lo = 0.f, c_hi = 0.f;

    int sv = (layer == 0) ? src[b_a * SEQ] : 0;   // prefetched src token

    for (int t = 0; t < SEQ; ++t) {
        f32x4 acc0 = {0.f, 0.f, 0.f, 0.f};
        f32x4 acc1 = {0.f, 0.f, 0.f, 0.f};

        if (layer == 0) {
            // ---- x @ W_ih^T from embedding: NO cross-WG dependency -> before any wait.
            //      chunked f32 register staging so loads cluster (4 x 16 f32x4) ----
            const float* xF = Wemb + (size_t)sv * HID + kq;
            if (t + 1 < SEQ) sv = src[b_a * SEQ + t + 1];   // prefetch next token id
#pragma unroll
            for (int c = 0; c < 4; ++c) {
                f32x4 xv[16];
#pragma unroll
                for (int i = 0; i < 8; ++i) {
                    const float* p = xF + (c * 8 + i) * 32;
                    xv[2 * i]     = *(const f32x4*)p;
                    xv[2 * i + 1] = *(const f32x4*)(p + 4);
                }
#pragma unroll
                for (int i = 0; i < 8; ++i) {
                    const int k = (c * 8 + i) * 32 + kq;
                    s16x8 af;
#pragma unroll
                    for (int j = 0; j < 4; ++j) {
                        af[j]     = f2bf(xv[2 * i][j]);
                        af[4 + j] = f2bf(xv[2 * i + 1][j]);
                    }
                    s16x8 b0 = *(const s16x8*)&slab[m][k];
                    s16x8 b1 = *(const s16x8*)&slab[16 + m][k];
                    acc0 = __builtin_amdgcn_mfma_f32_16x16x32_bf16(af, b0, acc0, 0, 0, 0);
                    acc1 = __builtin_amdgcn_mfma_f32_16x16x32_bf16(af, b1, acc1, 0, 0, 0);
                }
            }
            // A: own layer finished step t-1 -> h0[t-1] readable
            wait16(g0, tid, 8 * t);
            // ---- h @ W_hh^T (batched coherent loads) ----
            gemm_bt(h0 + (size_t)((t - 1) & (H0_SLOTS - 1)) * BH + b_a * HID + kq,
                    &slab[m][HID + kq], &slab[16 + m][HID + kq], acc0, acc1);
        } else {
            // A: layer0 finished step t -> h0[t] readable
            wait16(g0, tid, 8 * (t + 1));
            // ---- x @ W_ih^T where x = h0[t] ----
            gemm_bt(h0 + (size_t)(t & (H0_SLOTS - 1)) * BH + b_a * HID + kq,
                    &slab[m][kq], &slab[16 + m][kq], acc0, acc1);
            // B: own layer finished step t-1 -> h1[t-1] readable
            wait16(g1, tid, 8 * t);
            // ---- h @ W_hh^T ----
            gemm_bt(h1 + (size_t)((t - 1) & (H1_SLOTS - 1)) * BH + b_a * HID + kq,
                    &slab[m][HID + kq], &slab[16 + m][HID + kq], acc0, acc1);
        }

        // C/D layout: col = lane&15, row = (lane>>4)*4 + r  (verified m89/m91)
        const int rowg = wave * 16 + (lane >> 4) * 4;
#pragma unroll
        for (int r = 0; r < 4; ++r) {
            gates[rowg + r][m]      = acc0[r];
            gates[rowg + r][16 + m] = acc1[r];
        }

        // pre-epilogue barrier; L0 additionally ring-protects its h0 slot write:
        // B: layer1 finished step t-4 (only guards the epilogue store, so it sits
        // AFTER both GEMMs, off the recurrence critical path)
        if (layer == 0) wait16(g1, tid, 8 * (t - 3));
        else            __syncthreads();

        // ---- epilogue: 2 adjacent units per thread, c-state in registers ----
        {
            float gi0 = gates[bb][u0]      + bias[u0];
            float gi1 = gates[bb][u0 + 1]  + bias[u0 + 1];
            float gf0 = gates[bb][u0 + 8]  + bias[u0 + 8];
            float gf1 = gates[bb][u0 + 9]  + bias[u0 + 9];
            float gg0 = gates[bb][u0 + 16] + bias[u0 + 16];
            float gg1 = gates[bb][u0 + 17] + bias[u0 + 17];
            float go0 = gates[bb][u0 + 24] + bias[u0 + 24];
            float go1 = gates[bb][u0 + 25] + bias[u0 + 25];
            float si0 = 1.f / (1.f + __expf(-gi0)), si1 = 1.f / (1.f + __expf(-gi1));
            float sf0 = 1.f / (1.f + __expf(-gf0)), sf1 = 1.f / (1.f + __expf(-gf1));
            float so0 = 1.f / (1.f + __expf(-go0)), so1 = 1.f / (1.f + __expf(-go1));
            float tg0 = tanhf(gg0), tg1 = tanhf(gg1);
            c_lo = sf0 * c_lo + si0 * tg0;
            c_hi = sf1 * c_hi + si1 * tg1;
            float h_lo = so0 * tanhf(c_lo);
            float h_hi = so1 * tanhf(c_hi);

            bf16* hw = ((layer == 0) ? h0 + (size_t)(t & (H0_SLOTS - 1)) * BH
                                     : h1 + (size_t)(t & (H1_SLOTS - 1)) * BH);
            unsigned int hp = (unsigned int)(unsigned short)f2bf(h_lo) |
                              ((unsigned int)(unsigned short)f2bf(h_hi) << 16);
            __hip_atomic_store((unsigned int*)(hw + bb * HID + j0 + u0), hp,
                               __ATOMIC_RELAXED, __HIP_MEMORY_SCOPE_AGENT);
            if (layer == 1) {
                float2 hv = make_float2(h_lo, h_hi);
                *(float2*)(out + ((size_t)bb * SEQ + t) * HID + j0 + u0) = hv;
            }
            if (t == SEQ - 1) {
                size_t o = ((size_t)layer * BATCH + bb) * HID + j0 + u0;
                *(float2*)(out + OUT_HN + o) = make_float2(h_lo, h_hi);
                *(float2*)(out + OUT_CN + o) = make_float2(c_lo, c_hi);
            }
        }
        __syncthreads();   // drains vmcnt(0): all h stores at coherent point
        if (tid == 0)
            __hip_atomic_fetch_add(grp, 1u, __ATOMIC_RELAXED, __HIP_MEMORY_SCOPE_AGENT);
    }
}

extern "C" void kernel_launch(void* const* d_in, const int* in_sizes, int n_in,
                              void* d_out, int out_size, void* d_ws, size_t ws_size,
                              hipStream_t stream) {
    const int*   src  = (const int*)d_in[0];
    const float* emb  = (const float*)d_in[1];
    const float* W_ih = (const float*)d_in[2];
    const float* W_hh = (const float*)d_in[3];
    const float* b_ih = (const float*)d_in[4];
    const float* b_hh = (const float*)d_in[5];
    float* out  = (float*)d_out;
    bf16*  hbuf = (bf16*)d_ws;                 // uses 790,784 B

    // zero h rings + flag lines (ws is re-poisoned 0xAA before every replay)
    unsigned int* wsp = (unsigned int*)d_ws;
    int n = (int)(WS_BYTES / 4);
    ws_init<<<256, 256, 0, stream>>>(wsp, n);

    void* args[] = {&src, &emb, &W_ih, &W_hh, &b_ih, &b_hh, &out, &hbuf};
    hipLaunchCooperativeKernel((void*)lstm_enc, dim3(NWG), dim3(THREADS),
                               args, 0, stream);
}